// Round 7
// baseline (1832.209 us; speedup 1.0000x reference)
//
#include <hip/hip_runtime.h>
#include <hip/hip_bf16.h>

#define T 256
#define H 400
#define G4 1600   // 4*H
#define WD 300
#define TD 100
#define MLP_H 400
#define NBLK_D 5        // blocks per direction
#define NPAIR 200       // 400 h values -> 200 tagged 64-bit words

typedef _Float16 f16;
typedef _Float16 half2t __attribute__((ext_vector_type(2)));
typedef unsigned long long u64;
typedef unsigned int u32;

// ---------- math helpers ----------
__device__ __forceinline__ float fexp(float x) {
    return __builtin_amdgcn_exp2f(x * 1.4426950408889634f);
}
__device__ __forceinline__ float sigf(float x) {
    return __builtin_amdgcn_rcpf(1.0f + fexp(-x));
}
__device__ __forceinline__ float tanhf_fast(float x) {
    return 1.0f - 2.0f * __builtin_amdgcn_rcpf(1.0f + fexp(2.0f * x));
}
__device__ __forceinline__ unsigned short f16bits(f16 x) {
    union { f16 h; unsigned short u; } v; v.h = x; return v.u;
}
__device__ __forceinline__ u32 packh2(float a, float b) {
    half2t hv; hv.x = (_Float16)a; hv.y = (_Float16)b;
    return __builtin_bit_cast(u32, hv);
}

#if __has_builtin(__builtin_amdgcn_fdot2)
__device__ __forceinline__ float dot2u(u32 a, u32 b, float c) {
    return __builtin_amdgcn_fdot2(__builtin_bit_cast(half2t, a),
                                  __builtin_bit_cast(half2t, b), c, false);
}
#else
__device__ __forceinline__ float dot2u(u32 a, u32 b, float c) {
    half2t x = __builtin_bit_cast(half2t, a), y = __builtin_bit_cast(half2t, b);
    return fmaf((float)x.y, (float)y.y, fmaf((float)x.x, (float)y.x, c));
}
#endif

// system-scope (sc0 sc1) plain ops: bypass L1/L2, serviced at the IC --
// coherent across XCDs without RMWs or fences.
__device__ __forceinline__ u64 sysload(const u64* p) {
    return __hip_atomic_load(p, __ATOMIC_RELAXED, __HIP_MEMORY_SCOPE_SYSTEM);
}
__device__ __forceinline__ void sysstore(u64* p, u64 v) {
    __hip_atomic_store(p, v, __ATOMIC_RELAXED, __HIP_MEMORY_SCOPE_SYSTEM);
}

// ---------- embedding gather ----------
__global__ void gather_k(const int* __restrict__ words, const int* __restrict__ tags,
                         const float* __restrict__ wemb, const float* __restrict__ temb,
                         float* __restrict__ x0) {
    int t = blockIdx.x;
    int w = words[t], g = tags[t];
    for (int c = threadIdx.x; c < H; c += 128) {
        float v = (c < WD) ? wemb[w * WD + c] : temb[g * TD + (c - WD)];
        x0[t * H + c] = v;
    }
}

// ---------- generic GEMM: out[t][r] = sum_k X[t*ldx+k]*W[r*ldw+wofs+k] + bias1[r]+bias2[r]
__global__ __launch_bounds__(256) void gemm_tn(
    const float* __restrict__ X, int ldx,
    const float* __restrict__ Wt, int ldw, int wofs,
    const float* __restrict__ bias1, const float* __restrict__ bias2,
    float* __restrict__ out, int ldo, int Rt, int K) {
    __shared__ float Xs[64][17];
    __shared__ float Ws[64][17];
    const int tid = threadIdx.x;
    const int t0 = blockIdx.x * 64, r0 = blockIdx.y * 64;
    const int lr = tid >> 2, kq = (tid & 3) * 4;
    const int ti = tid >> 4, rj = tid & 15;
    float acc[4][4] = {};
    for (int k0 = 0; k0 < K; k0 += 16) {
        float4 xv = *(const float4*)(X + (size_t)(t0 + lr) * ldx + k0 + kq);
        Xs[lr][kq + 0] = xv.x; Xs[lr][kq + 1] = xv.y;
        Xs[lr][kq + 2] = xv.z; Xs[lr][kq + 3] = xv.w;
        int r = r0 + lr;
        float4 wv = make_float4(0.f, 0.f, 0.f, 0.f);
        if (r < Rt) wv = *(const float4*)(Wt + (size_t)r * ldw + wofs + k0 + kq);
        Ws[lr][kq + 0] = wv.x; Ws[lr][kq + 1] = wv.y;
        Ws[lr][kq + 2] = wv.z; Ws[lr][kq + 3] = wv.w;
        __syncthreads();
#pragma unroll
        for (int k = 0; k < 16; k++) {
            float xr[4], wr[4];
#pragma unroll
            for (int m = 0; m < 4; m++) xr[m] = Xs[ti * 4 + m][k];
#pragma unroll
            for (int n = 0; n < 4; n++) wr[n] = Ws[rj * 4 + n][k];
#pragma unroll
            for (int m = 0; m < 4; m++)
#pragma unroll
                for (int n = 0; n < 4; n++)
                    acc[m][n] = fmaf(xr[m], wr[n], acc[m][n]);
        }
        __syncthreads();
    }
    int rq = r0 + rj * 4;
    if (rq < Rt) {
        float b[4];
#pragma unroll
        for (int n = 0; n < 4; n++) {
            int r = rq + n;
            b[n] = (bias1 ? bias1[r] : 0.f) + (bias2 ? bias2[r] : 0.f);
        }
#pragma unroll
        for (int m = 0; m < 4; m++) {
            int t = t0 + ti * 4 + m;
            float4 o;
            o.x = acc[m][0] + b[0]; o.y = acc[m][1] + b[1];
            o.z = acc[m][2] + b[2]; o.w = acc[m][3] + b[3];
            *(float4*)(out + (size_t)t * ldo + rq) = o;
        }
    }
}

// ---------- init: tagged words, contiguous [dir][parity][NPAIR] ----------
__global__ void lstm_init5(const float* __restrict__ h0, u64* sA, u64* sB) {
    int tid = threadIdx.x;
    const int TOT = 2 * 2 * NPAIR;
    for (int i = tid; i < TOT; i += 256) { sA[i] = 0xFFFFULL; sB[i] = 0xFFFFULL; }
    __syncthreads();
    for (int p = tid; p < 2 * NPAIR; p += 256) {
        int d = p / NPAIR, pr = p - d * NPAIR;
        size_t off = (size_t)(d * 2 + 0) * NPAIR + pr;   // parity 0, tag 0
        f16 a0 = (f16)h0[d * H + 2 * pr], b0 = (f16)h0[d * H + 2 * pr + 1];
        sA[off] = 0ULL | ((u64)f16bits(a0) << 16) | ((u64)f16bits(b0) << 32);
        f16 a1 = (f16)h0[2 * H + d * H + 2 * pr], b1 = (f16)h0[2 * H + d * H + 2 * pr + 1];
        sB[off] = 0ULL | ((u64)f16bits(a1) << 16) | ((u64)f16bits(b1) << 32);
    }
}

// ---------- persistent LSTM layer v7: register-pinned weights ----------
// grid = 10 blocks (dir = b/5, blk = b%5), 512 threads.
// Block owns h rows [blk*80,+80). Workers tid<320: one full gate-row each,
// 200 packed-half2 weights PINNED in VGPRs via asm (compiler cannot sink the
// loads back into the loop -- R6's VGPR_Count=128 showed it rematerialized
// them from L2 every step, ~1.7us/step). 4 independent dot accumulators.
// tid in [320,480): pollers (R5 sc0/sc1 tagged words). tid>=480: G stagers.
__global__ __launch_bounds__(512, 2) void lstm_layer7(
    const float* __restrict__ G,     // [2][T][G4] gate inputs, biases folded
    const float* __restrict__ Whh,   // [2][G4][H]
    const float* __restrict__ c0l,   // [2][H] this layer
    float* __restrict__ xout,        // [T][2H]
    u64* __restrict__ slots) {       // [2][2][NPAIR]
    const int role = blockIdx.x;
    const int dir = role / NBLK_D, blk = role - dir * NBLK_D;
    const int tid = threadIdx.x;
    const float* Wd = Whh + (size_t)dir * G4 * H;
    const float* Gd = G + (size_t)dir * T * G4;
    u64* sd = slots + (size_t)dir * 2 * NPAIR;

    __shared__ __align__(16) u32 hsh[NPAIR];   // h_s as 200 packed half2
    __shared__ float gsum[320];                // per-gate-row matvec sums
    __shared__ float gsh[2][320];              // staged G, double-buffered
    __shared__ f16 hpub[80];

    f16* hsh16 = (f16*)hsh;

    const bool worker = tid < 320;
    const int g = tid / 80;            // gate (workers only)
    const int r = tid - g * 80;        // local row (workers only)

    // worker: load one full gate-row of Whh, pack to half2, PIN in VGPRs
    u32 w[200];
    {
        // non-workers read row 0 (harmless) so the asm pin below is uniform
        int row_idx = worker ? (g * H + blk * 80 + r) : 0;
        const float4* row = (const float4*)(Wd + (size_t)row_idx * H);
#pragma unroll
        for (int i = 0; i < 100; ++i) {
            float4 f = row[i];
            w[2 * i]     = packh2(f.x, f.y);
            w[2 * i + 1] = packh2(f.z, f.w);
        }
    }
#pragma unroll
    for (int i = 0; i < 200; ++i) asm volatile("" : "+v"(w[i]));  // pin

    float c = (tid < 80) ? c0l[dir * H + blk * 80 + tid] : 0.f;

    // pre-loop: stagers stage G(0); tid<40 loads own h0 words into LDS
    if (tid >= 480) {
        int tt0 = dir ? (T - 1) : 0;
        for (int i = tid - 480; i < 320; i += 32) {
            int gg = i / 80, rr = i - gg * 80;
            gsh[0][i] = Gd[(size_t)tt0 * G4 + gg * H + blk * 80 + rr];
        }
    } else if (tid < 40) {
        u64 v = sysload(sd + blk * 40 + tid);      // parity 0, tag 0
        hsh[blk * 40 + tid] = (u32)(v >> 16);
    }

#pragma clang loop unroll(disable)
    for (int s = 0; s < T; ++s) {
        if (tid >= 320) {
            if (tid < 480) {
                // poller: one foreign word (parity s&1, tag s)
                int f = tid - 320;
                int widx = f + (f >= blk * 40 ? 40 : 0);
                u64* src = sd + (size_t)(s & 1) * NPAIR + widx;
                u64 v = sysload(src);
                int spins = 0;
                while ((unsigned)(v & 0xFFFFULL) != (unsigned)s) {
                    if (++spins > 16384) {
                        v = __hip_atomic_fetch_add(src, 0ULL, __ATOMIC_RELAXED,
                                                   __HIP_MEMORY_SCOPE_AGENT);
                    } else {
                        v = sysload(src);
                    }
                }
                hsh[widx] = (u32)(v >> 16);
            } else {
                // stager: G(s+1) into the other parity half
                int sn = (s + 1 < T) ? (s + 1) : s;
                int tt = dir ? (T - 1 - sn) : sn;
                for (int i = tid - 480; i < 320; i += 32) {
                    int gg = i / 80, rr = i - gg * 80;
                    gsh[(s + 1) & 1][i] = Gd[(size_t)tt * G4 + gg * H + blk * 80 + rr];
                }
            }
        }
        __syncthreads();   // (A) h_s complete in LDS

        if (worker) {
            const uint4* hp = (const uint4*)hsh;   // broadcast b128 reads
            float a0 = 0.f, a1 = 0.f, a2 = 0.f, a3 = 0.f;
#pragma unroll
            for (int i = 0; i < 50; ++i) {
                uint4 q = hp[i];
                a0 = dot2u(w[4 * i + 0], q.x, a0);
                a1 = dot2u(w[4 * i + 1], q.y, a1);
                a2 = dot2u(w[4 * i + 2], q.z, a2);
                a3 = dot2u(w[4 * i + 3], q.w, a3);
            }
            gsum[tid] = (a0 + a1) + (a2 + a3);
        }
        __syncthreads();   // (B) sums ready; all done reading hsh

        const int tt = dir ? (T - 1 - s) : s;
        float hn = 0.f;
        if (tid < 80) {
            const float* gc = gsh[s & 1];
            float iv = gsum[tid]        + gc[tid];
            float fv = gsum[80 + tid]   + gc[80 + tid];
            float gv = gsum[160 + tid]  + gc[160 + tid];
            float ov = gsum[240 + tid]  + gc[240 + tid];
            float cn = sigf(fv) * c + sigf(iv) * tanhf_fast(gv);
            c = cn;
            hn = sigf(ov) * tanhf_fast(cn);
            f16 hf = (f16)hn;
            hpub[tid] = hf;
            hsh16[blk * 80 + tid] = hf;    // own slice of h_{s+1}, LDS fast-path
        }
        __syncthreads();   // (C) hpub/own-h ready

        if (tid < 40) {
            // publish first: this is the cross-block critical path
            u32 pk = (u32)f16bits(hpub[2 * tid]) | ((u32)f16bits(hpub[2 * tid + 1]) << 16);
            sysstore(sd + (size_t)((s + 1) & 1) * NPAIR + blk * 40 + tid,
                     (u64)(unsigned)(s + 1) | ((u64)pk << 16));
        }
        if (tid < 80) {
            // xout store off the publish path
            xout[(size_t)tt * (2 * H) + dir * H + blk * 80 + tid] = hn;
        }
    }
}

// ---------- fused pairwise scorer ----------
__global__ __launch_bounds__(256) void scores_k(
    const float* __restrict__ pi, const float* __restrict__ pj,
    const float* __restrict__ w2, const float* __restrict__ b2p,
    float* __restrict__ out) {
    __shared__ float Ps[16][401];
    __shared__ float Qs[16][401];
    __shared__ float w2s[400];
    const int tid = threadIdx.x;
    const int i0 = blockIdx.y * 16, j0 = blockIdx.x * 16;
    for (int r = 0; r < 16; r++) {
        for (int k = tid; k < MLP_H; k += 256) {
            Ps[r][k] = pi[(size_t)(i0 + r) * MLP_H + k];
            Qs[r][k] = pj[(size_t)(j0 + r) * MLP_H + k];
        }
    }
    for (int k = tid; k < MLP_H; k += 256) w2s[k] = w2[k];
    __syncthreads();
    const int ti = tid >> 4, tj = tid & 15;
    float acc = 0.f;
#pragma unroll 4
    for (int k = 0; k < MLP_H; k++) {
        float x = Ps[ti][k] + Qs[tj][k];
        acc = fmaf(w2s[k], tanhf_fast(x), acc);
    }
    const int i = i0 + ti, j = j0 + tj;
    out[(size_t)i * T + j] = (i == j) ? 0.f : (acc + b2p[0]);
}

extern "C" void kernel_launch(void* const* d_in, const int* in_sizes, int n_in,
                              void* d_out, int out_size, void* d_ws, size_t ws_size,
                              hipStream_t stream) {
    const int*   words = (const int*)d_in[0];
    const int*   tags  = (const int*)d_in[1];
    const float* wemb  = (const float*)d_in[2];
    const float* temb  = (const float*)d_in[3];
    const float* Wih0  = (const float*)d_in[4];
    const float* Whh0  = (const float*)d_in[5];
    const float* bih0  = (const float*)d_in[6];
    const float* bhh0  = (const float*)d_in[7];
    const float* Wih1  = (const float*)d_in[8];
    const float* Whh1  = (const float*)d_in[9];
    const float* bih1  = (const float*)d_in[10];
    const float* bhh1  = (const float*)d_in[11];
    const float* W1    = (const float*)d_in[12];
    const float* b1    = (const float*)d_in[13];
    const float* W2    = (const float*)d_in[14];
    const float* b2    = (const float*)d_in[15];
    const float* h0    = (const float*)d_in[16];
    const float* c0    = (const float*)d_in[17];
    float* out = (float*)d_out;

    float* W = (float*)d_ws;
    float* x0   = W;                 // 256*400 (dead after layer-0 GEMMs)
    float* x1   = W + 102400;        // 256*800
    float* hvec = W + 307200;        // 256*800
    float* Gb   = W + 512000;        // 2*256*1600 (reused for both layers)
    float* pi   = W + 1331200;       // 256*400
    float* pj   = W + 1433600;       // 256*400
    // word arrays overlap x0's region (x0 dead before lstm_init5 runs)
    u64* slotsA = (u64*)W;                               // 800 u64
    u64* slotsB = (u64*)(W + 2048);                      // 800 u64

    // 1. embedding gather
    gather_k<<<T, 128, 0, stream>>>(words, tags, wemb, temb, x0);

    // 2. layer-0 gate inputs
    for (int d = 0; d < 2; d++) {
        gemm_tn<<<dim3(4, 25), 256, 0, stream>>>(
            x0, H, Wih0 + (size_t)d * G4 * H, H, 0,
            bih0 + d * G4, bhh0 + d * G4,
            Gb + (size_t)d * T * G4, G4, G4, H);
    }
    // 3. init tagged words (x0 now dead), then LSTM layer 0
    lstm_init5<<<1, 256, 0, stream>>>(h0, slotsA, slotsB);
    lstm_layer7<<<2 * NBLK_D, 512, 0, stream>>>(Gb, Whh0, c0, x1, slotsA);

    // 4. layer-1 gate inputs (K=800)
    for (int d = 0; d < 2; d++) {
        gemm_tn<<<dim3(4, 25), 256, 0, stream>>>(
            x1, 2 * H, Wih1 + (size_t)d * G4 * (2 * H), 2 * H, 0,
            bih1 + d * G4, bhh1 + d * G4,
            Gb + (size_t)d * T * G4, G4, G4, 2 * H);
    }
    // 5. LSTM layer 1
    lstm_layer7<<<2 * NBLK_D, 512, 0, stream>>>(Gb, Whh1, c0 + 2 * H, hvec, slotsB);

    // 6. pi = hvec @ W1a.T + b1 ; pj = hvec @ W1b.T
    gemm_tn<<<dim3(4, 7), 256, 0, stream>>>(
        hvec, 2 * H, W1, G4, 0, b1, nullptr, pi, MLP_H, MLP_H, 2 * H);
    gemm_tn<<<dim3(4, 7), 256, 0, stream>>>(
        hvec, 2 * H, W1, G4, 2 * H, nullptr, nullptr, pj, MLP_H, MLP_H, 2 * H);

    // 7. fused pairwise scores
    scores_k<<<dim3(16, 16), 256, 0, stream>>>(pi, pj, W2, b2, out);
}

// Round 8
// 1438.542 us; speedup vs baseline: 1.2737x; 1.2737x over previous
//
#include <hip/hip_runtime.h>
#include <hip/hip_bf16.h>

#define T 256
#define H 400
#define G4 1600   // 4*H
#define WD 300
#define TD 100
#define MLP_H 400
#define NBLK_D 25       // blocks per direction (50 total)
#define HB 16           // h-rows per block
#define GR 64           // gate-rows per block (4*HB)
#define WSTR 202        // LDS weight row stride in u32 (bank-conflict pad)
#define NPAIR 200       // 400 h values -> 200 tagged 64-bit words

typedef _Float16 f16;
typedef _Float16 half2t __attribute__((ext_vector_type(2)));
typedef unsigned long long u64;
typedef unsigned int u32;

// ---------- math helpers ----------
__device__ __forceinline__ float fexp(float x) {
    return __builtin_amdgcn_exp2f(x * 1.4426950408889634f);
}
__device__ __forceinline__ float sigf(float x) {
    return __builtin_amdgcn_rcpf(1.0f + fexp(-x));
}
__device__ __forceinline__ float tanhf_fast(float x) {
    return 1.0f - 2.0f * __builtin_amdgcn_rcpf(1.0f + fexp(2.0f * x));
}
__device__ __forceinline__ unsigned short f16bits(f16 x) {
    union { f16 h; unsigned short u; } v; v.h = x; return v.u;
}
__device__ __forceinline__ u32 packh2(float a, float b) {
    half2t hv; hv.x = (_Float16)a; hv.y = (_Float16)b;
    return __builtin_bit_cast(u32, hv);
}

#if __has_builtin(__builtin_amdgcn_fdot2)
__device__ __forceinline__ float dot2u(u32 a, u32 b, float c) {
    return __builtin_amdgcn_fdot2(__builtin_bit_cast(half2t, a),
                                  __builtin_bit_cast(half2t, b), c, false);
}
#else
__device__ __forceinline__ float dot2u(u32 a, u32 b, float c) {
    half2t x = __builtin_bit_cast(half2t, a), y = __builtin_bit_cast(half2t, b);
    return fmaf((float)x.y, (float)y.y, fmaf((float)x.x, (float)y.x, c));
}
#endif

// system-scope (sc0 sc1) plain ops: bypass L1/L2, serviced at the IC --
// coherent across XCDs without RMWs or fences.
__device__ __forceinline__ u64 sysload(const u64* p) {
    return __hip_atomic_load(p, __ATOMIC_RELAXED, __HIP_MEMORY_SCOPE_SYSTEM);
}
__device__ __forceinline__ void sysstore(u64* p, u64 v) {
    __hip_atomic_store(p, v, __ATOMIC_RELAXED, __HIP_MEMORY_SCOPE_SYSTEM);
}

// ---------- embedding gather ----------
__global__ void gather_k(const int* __restrict__ words, const int* __restrict__ tags,
                         const float* __restrict__ wemb, const float* __restrict__ temb,
                         float* __restrict__ x0) {
    int t = blockIdx.x;
    int w = words[t], g = tags[t];
    for (int c = threadIdx.x; c < H; c += 128) {
        float v = (c < WD) ? wemb[w * WD + c] : temb[g * TD + (c - WD)];
        x0[t * H + c] = v;
    }
}

// ---------- generic GEMM: out[t][r] = sum_k X[t*ldx+k]*W[r*ldw+wofs+k] + bias1[r]+bias2[r]
__global__ __launch_bounds__(256) void gemm_tn(
    const float* __restrict__ X, int ldx,
    const float* __restrict__ Wt, int ldw, int wofs,
    const float* __restrict__ bias1, const float* __restrict__ bias2,
    float* __restrict__ out, int ldo, int Rt, int K) {
    __shared__ float Xs[64][17];
    __shared__ float Ws[64][17];
    const int tid = threadIdx.x;
    const int t0 = blockIdx.x * 64, r0 = blockIdx.y * 64;
    const int lr = tid >> 2, kq = (tid & 3) * 4;
    const int ti = tid >> 4, rj = tid & 15;
    float acc[4][4] = {};
    for (int k0 = 0; k0 < K; k0 += 16) {
        float4 xv = *(const float4*)(X + (size_t)(t0 + lr) * ldx + k0 + kq);
        Xs[lr][kq + 0] = xv.x; Xs[lr][kq + 1] = xv.y;
        Xs[lr][kq + 2] = xv.z; Xs[lr][kq + 3] = xv.w;
        int r = r0 + lr;
        float4 wv = make_float4(0.f, 0.f, 0.f, 0.f);
        if (r < Rt) wv = *(const float4*)(Wt + (size_t)r * ldw + wofs + k0 + kq);
        Ws[lr][kq + 0] = wv.x; Ws[lr][kq + 1] = wv.y;
        Ws[lr][kq + 2] = wv.z; Ws[lr][kq + 3] = wv.w;
        __syncthreads();
#pragma unroll
        for (int k = 0; k < 16; k++) {
            float xr[4], wr[4];
#pragma unroll
            for (int m = 0; m < 4; m++) xr[m] = Xs[ti * 4 + m][k];
#pragma unroll
            for (int n = 0; n < 4; n++) wr[n] = Ws[rj * 4 + n][k];
#pragma unroll
            for (int m = 0; m < 4; m++)
#pragma unroll
                for (int n = 0; n < 4; n++)
                    acc[m][n] = fmaf(xr[m], wr[n], acc[m][n]);
        }
        __syncthreads();
    }
    int rq = r0 + rj * 4;
    if (rq < Rt) {
        float b[4];
#pragma unroll
        for (int n = 0; n < 4; n++) {
            int r = rq + n;
            b[n] = (bias1 ? bias1[r] : 0.f) + (bias2 ? bias2[r] : 0.f);
        }
#pragma unroll
        for (int m = 0; m < 4; m++) {
            int t = t0 + ti * 4 + m;
            float4 o;
            o.x = acc[m][0] + b[0]; o.y = acc[m][1] + b[1];
            o.z = acc[m][2] + b[2]; o.w = acc[m][3] + b[3];
            *(float4*)(out + (size_t)t * ldo + rq) = o;
        }
    }
}

// ---------- init: tagged words, contiguous [dir][parity][NPAIR] ----------
__global__ void lstm_init5(const float* __restrict__ h0, u64* sA, u64* sB) {
    int tid = threadIdx.x;
    const int TOT = 2 * 2 * NPAIR;
    for (int i = tid; i < TOT; i += 256) { sA[i] = 0xFFFFULL; sB[i] = 0xFFFFULL; }
    __syncthreads();
    for (int p = tid; p < 2 * NPAIR; p += 256) {
        int d = p / NPAIR, pr = p - d * NPAIR;
        size_t off = (size_t)(d * 2 + 0) * NPAIR + pr;   // parity 0, tag 0
        f16 a0 = (f16)h0[d * H + 2 * pr], b0 = (f16)h0[d * H + 2 * pr + 1];
        sA[off] = 0ULL | ((u64)f16bits(a0) << 16) | ((u64)f16bits(b0) << 32);
        f16 a1 = (f16)h0[2 * H + d * H + 2 * pr], b1 = (f16)h0[2 * H + d * H + 2 * pr + 1];
        sB[off] = 0ULL | ((u64)f16bits(a1) << 16) | ((u64)f16bits(b1) << 32);
    }
}

// ---------- persistent LSTM layer v8: LDS-resident weights ----------
// grid = 50 blocks (dir = b/25, blk = b%25), 512 threads.
// Block owns h rows [blk*16,+16) = 64 gate-rows. Weights live in LDS
// (50.5 KiB, loaded once) -- R6/R7 proved the register allocator will not
// hold them in VGPRs (rematerialized from L2 every step, ~1.7us/step).
// tid<256: workers, 4 per gate-row (row=tid>>2, slice=tid&3, 50 packed
// half2 each), combine via 2 shfl_xor. tid in [256,448): pollers for the
// 192 foreign tagged words (R5 sc0/sc1 scheme). tid>=448: G stagers.
// Wave 0 does gate math + publish via intra-wave shuffles. 2 barriers/step.
__global__ __launch_bounds__(512, 1) void lstm_layer8(
    const float* __restrict__ G,     // [2][T][G4] gate inputs, biases folded
    const float* __restrict__ Whh,   // [2][G4][H]
    const float* __restrict__ c0l,   // [2][H] this layer
    float* __restrict__ xout,        // [T][2H]
    u64* __restrict__ slots) {       // [2][2][NPAIR]
    const int role = blockIdx.x;
    const int dir = role / NBLK_D, blk = role - dir * NBLK_D;
    const int tid = threadIdx.x;
    const float* Wd = Whh + (size_t)dir * G4 * H;
    const float* Gd = G + (size_t)dir * T * G4;
    u64* sd = slots + (size_t)dir * 2 * NPAIR;

    __shared__ u32 wlds[GR * WSTR];            // 64 rows x 202 u32 = 50.5 KiB
    __shared__ __align__(16) u32 hsh[NPAIR];   // h_s as 200 packed half2
    __shared__ float gsum[GR];                 // per-gate-row matvec sums
    __shared__ float gsh[2][GR];               // staged G, double-buffered

    // ---- one-time: pack weights fp32 -> half2 into LDS ----
    for (int idx = tid; idx < GR * 100; idx += 512) {
        int row = idx / 100, c4 = idx - row * 100;
        int g = row >> 4, r = row & 15;
        const float4* src = (const float4*)(Wd + (size_t)(g * H + blk * HB + r) * H);
        float4 f = src[c4];
        *(uint2*)&wlds[row * WSTR + c4 * 2] =
            make_uint2(packh2(f.x, f.y), packh2(f.z, f.w));
    }
    // pre-stage G(0); own h0 words into LDS
    if (tid >= 448) {
        int i = tid - 448, gg = i >> 4, rr = i & 15;
        int tt0 = dir ? (T - 1) : 0;
        gsh[0][i] = Gd[(size_t)tt0 * G4 + gg * H + blk * HB + rr];
    } else if (tid < 8) {
        u64 v = sysload(sd + blk * 8 + tid);       // parity 0, tag 0
        hsh[blk * 8 + tid] = (u32)(v >> 16);
    }
    float c = (tid < 64) ? c0l[dir * H + blk * HB + (tid & 15)] : 0.f;
    __syncthreads();

#pragma clang loop unroll(disable)
    for (int s = 0; s < T; ++s) {
        if (tid >= 256 && tid < 448) {
            // poller: one foreign word (parity s&1, tag s)
            int f = tid - 256;
            int widx = f + (f >= blk * 8 ? 8 : 0);
            u64* src = sd + (size_t)(s & 1) * NPAIR + widx;
            u64 v = sysload(src);
            int spins = 0;
            while ((unsigned)(v & 0xFFFFULL) != (unsigned)s) {
                if (++spins > 16384) {
                    v = __hip_atomic_fetch_add(src, 0ULL, __ATOMIC_RELAXED,
                                               __HIP_MEMORY_SCOPE_AGENT);
                } else {
                    v = sysload(src);
                }
            }
            hsh[widx] = (u32)(v >> 16);
        } else if (tid >= 448) {
            // stager: G(s+1) into the other parity half
            int sn = (s + 1 < T) ? (s + 1) : s;
            int tt = dir ? (T - 1 - sn) : sn;
            int i = tid - 448, gg = i >> 4, rr = i & 15;
            gsh[(s + 1) & 1][i] = Gd[(size_t)tt * G4 + gg * H + blk * HB + rr];
        }
        __syncthreads();   // (A) h_s complete in LDS

        if (tid < 256) {
            const int row = tid >> 2, sl = tid & 3;
            const u32* wp = &wlds[row * WSTR + sl * 50];
            const u32* hp = &hsh[sl * 50];
            float a0 = 0.f, a1 = 0.f, a2 = 0.f, a3 = 0.f;
#pragma unroll
            for (int i = 0; i < 12; ++i) {
                uint2 wv0 = *(const uint2*)&wp[4 * i];
                uint2 hv0 = *(const uint2*)&hp[4 * i];
                uint2 wv1 = *(const uint2*)&wp[4 * i + 2];
                uint2 hv1 = *(const uint2*)&hp[4 * i + 2];
                a0 = dot2u(wv0.x, hv0.x, a0);
                a1 = dot2u(wv0.y, hv0.y, a1);
                a2 = dot2u(wv1.x, hv1.x, a2);
                a3 = dot2u(wv1.y, hv1.y, a3);
            }
            {
                uint2 wv = *(const uint2*)&wp[48];
                uint2 hv = *(const uint2*)&hp[48];
                a0 = dot2u(wv.x, hv.x, a0);
                a1 = dot2u(wv.y, hv.y, a1);
            }
            float a = (a0 + a1) + (a2 + a3);
            a += __shfl_xor(a, 1);    // combine the 4 k-slices (adjacent lanes)
            a += __shfl_xor(a, 2);
            if (sl == 0) gsum[row] = a;
        }
        __syncthreads();   // (B) sums ready

        if (tid < 64) {    // wave 0: gate math + publish, intra-wave only
            const int r = tid & 15;
            const float* gc = gsh[s & 1];
            float iv = gsum[r]      + gc[r];
            float fv = gsum[16 + r] + gc[16 + r];
            float gv = gsum[32 + r] + gc[32 + r];
            float ov = gsum[48 + r] + gc[48 + r];
            float cn = sigf(fv) * c + sigf(iv) * tanhf_fast(gv);
            c = cn;
            float hn = sigf(ov) * tanhf_fast(cn);
            u32 hb = (u32)f16bits((f16)hn);
            u32 lo = __shfl(hb, (2 * tid) & 63);
            u32 hi = __shfl(hb, (2 * tid + 1) & 63);
            if (tid < 8) {
                u32 pk = (lo & 0xFFFFu) | (hi << 16);
                hsh[blk * 8 + tid] = pk;   // own slice of h_{s+1}, LDS fast-path
                sysstore(sd + (size_t)((s + 1) & 1) * NPAIR + blk * 8 + tid,
                         (u64)(unsigned)(s + 1) | ((u64)pk << 16));
            }
            const int tt = dir ? (T - 1 - s) : s;
            if (tid < 16)
                xout[(size_t)tt * (2 * H) + dir * H + blk * HB + tid] = hn;
        }
    }
}

// ---------- fused pairwise scorer ----------
__global__ __launch_bounds__(256) void scores_k(
    const float* __restrict__ pi, const float* __restrict__ pj,
    const float* __restrict__ w2, const float* __restrict__ b2p,
    float* __restrict__ out) {
    __shared__ float Ps[16][401];
    __shared__ float Qs[16][401];
    __shared__ float w2s[400];
    const int tid = threadIdx.x;
    const int i0 = blockIdx.y * 16, j0 = blockIdx.x * 16;
    for (int r = 0; r < 16; r++) {
        for (int k = tid; k < MLP_H; k += 256) {
            Ps[r][k] = pi[(size_t)(i0 + r) * MLP_H + k];
            Qs[r][k] = pj[(size_t)(j0 + r) * MLP_H + k];
        }
    }
    for (int k = tid; k < MLP_H; k += 256) w2s[k] = w2[k];
    __syncthreads();
    const int ti = tid >> 4, tj = tid & 15;
    float acc = 0.f;
#pragma unroll 4
    for (int k = 0; k < MLP_H; k++) {
        float x = Ps[ti][k] + Qs[tj][k];
        acc = fmaf(w2s[k], tanhf_fast(x), acc);
    }
    const int i = i0 + ti, j = j0 + tj;
    out[(size_t)i * T + j] = (i == j) ? 0.f : (acc + b2p[0]);
}

extern "C" void kernel_launch(void* const* d_in, const int* in_sizes, int n_in,
                              void* d_out, int out_size, void* d_ws, size_t ws_size,
                              hipStream_t stream) {
    const int*   words = (const int*)d_in[0];
    const int*   tags  = (const int*)d_in[1];
    const float* wemb  = (const float*)d_in[2];
    const float* temb  = (const float*)d_in[3];
    const float* Wih0  = (const float*)d_in[4];
    const float* Whh0  = (const float*)d_in[5];
    const float* bih0  = (const float*)d_in[6];
    const float* bhh0  = (const float*)d_in[7];
    const float* Wih1  = (const float*)d_in[8];
    const float* Whh1  = (const float*)d_in[9];
    const float* bih1  = (const float*)d_in[10];
    const float* bhh1  = (const float*)d_in[11];
    const float* W1    = (const float*)d_in[12];
    const float* b1    = (const float*)d_in[13];
    const float* W2    = (const float*)d_in[14];
    const float* b2    = (const float*)d_in[15];
    const float* h0    = (const float*)d_in[16];
    const float* c0    = (const float*)d_in[17];
    float* out = (float*)d_out;

    float* W = (float*)d_ws;
    float* x0   = W;                 // 256*400 (dead after layer-0 GEMMs)
    float* x1   = W + 102400;        // 256*800
    float* hvec = W + 307200;        // 256*800
    float* Gb   = W + 512000;        // 2*256*1600 (reused for both layers)
    float* pi   = W + 1331200;       // 256*400
    float* pj   = W + 1433600;       // 256*400
    // word arrays overlap x0's region (x0 dead before lstm_init5 runs)
    u64* slotsA = (u64*)W;                               // 800 u64
    u64* slotsB = (u64*)(W + 2048);                      // 800 u64

    // 1. embedding gather
    gather_k<<<T, 128, 0, stream>>>(words, tags, wemb, temb, x0);

    // 2. layer-0 gate inputs
    for (int d = 0; d < 2; d++) {
        gemm_tn<<<dim3(4, 25), 256, 0, stream>>>(
            x0, H, Wih0 + (size_t)d * G4 * H, H, 0,
            bih0 + d * G4, bhh0 + d * G4,
            Gb + (size_t)d * T * G4, G4, G4, H);
    }
    // 3. init tagged words (x0 now dead), then LSTM layer 0
    lstm_init5<<<1, 256, 0, stream>>>(h0, slotsA, slotsB);
    lstm_layer8<<<2 * NBLK_D, 512, 0, stream>>>(Gb, Whh0, c0, x1, slotsA);

    // 4. layer-1 gate inputs (K=800)
    for (int d = 0; d < 2; d++) {
        gemm_tn<<<dim3(4, 25), 256, 0, stream>>>(
            x1, 2 * H, Wih1 + (size_t)d * G4 * (2 * H), 2 * H, 0,
            bih1 + d * G4, bhh1 + d * G4,
            Gb + (size_t)d * T * G4, G4, G4, 2 * H);
    }
    // 5. LSTM layer 1
    lstm_layer8<<<2 * NBLK_D, 512, 0, stream>>>(Gb, Whh1, c0 + 2 * H, hvec, slotsB);

    // 6. pi = hvec @ W1a.T + b1 ; pj = hvec @ W1b.T
    gemm_tn<<<dim3(4, 7), 256, 0, stream>>>(
        hvec, 2 * H, W1, G4, 0, b1, nullptr, pi, MLP_H, MLP_H, 2 * H);
    gemm_tn<<<dim3(4, 7), 256, 0, stream>>>(
        hvec, 2 * H, W1, G4, 2 * H, nullptr, nullptr, pj, MLP_H, MLP_H, 2 * H);

    // 7. fused pairwise scores
    scores_k<<<dim3(16, 16), 256, 0, stream>>>(pi, pj, W2, b2, out);
}